// Round 4
// baseline (1220.560 us; speedup 1.0000x reference)
//
#include <hip/hip_runtime.h>
#include <math.h>

typedef unsigned short ushort_t;
typedef unsigned int uint_t;
typedef __attribute__((ext_vector_type(8))) short bf16x8;
typedef __attribute__((ext_vector_type(4))) float f32x4;

#define NTOK 131072          // B*S
#define TM 16                // tokens per block
// SROW 520: 1040 B row = 65*16 -> b128 16B-aligned; 260 dw == 4 mod 32 -> free
// 2-way bank pattern (SROW=512 would be a 16-way conflict: 256 dw == 0 mod 32).
#define SROW 520
#define K0P 160              // layer0 K padded (132 -> 160) — Wt0 global layout
#define KHP 512              // hidden layers: te/pos folded out -> K = 512 exact
#define EPS 1e-5f

__device__ __forceinline__ ushort_t f2bf(float f) {
    uint_t x = __float_as_uint(f);
    x += 0x7FFFu + ((x >> 16) & 1u);   // RNE
    return (ushort_t)(x >> 16);
}
__device__ __forceinline__ float bf2f(ushort_t u) {
    return __uint_as_float(((uint_t)u) << 16);
}

#if defined(__has_builtin)
#  if __has_builtin(__builtin_amdgcn_cvt_pk_bf16_f32)
#    define HAVE_PK_BF16 1
#  endif
#  if __has_builtin(__builtin_amdgcn_rcpf)
#    define HAVE_RCPF 1
#  endif
#endif
__device__ __forceinline__ uint_t pk_bf16(float a, float b) {
#ifdef HAVE_PK_BF16
    auto r = __builtin_amdgcn_cvt_pk_bf16_f32(a, b);
    union { decltype(r) v; uint_t u; } cv; cv.v = r;
    return cv.u;
#else
    return (uint_t)f2bf(a) | ((uint_t)f2bf(b) << 16);
#endif
}
// approx reciprocal: v_rcp_f32 (1 op) instead of IEEE div (~9 ops). ~1 ulp —
// outputs are bf16-rounded, tolerance 1.2e-2; exactness not needed.
__device__ __forceinline__ float fastrcp(float x) {
#ifdef HAVE_RCPF
    return __builtin_amdgcn_rcpf(x);
#else
    return 1.0f / x;
#endif
}

// ---- DPP 16-lane rotation-reduction (all-reduce within each 16-lane row) ----
template<int CTRL>
__device__ __forceinline__ float row_ror_add(float v) {
    int r = __builtin_amdgcn_update_dpp(0, __float_as_int(v), CTRL, 0xF, 0xF, true);
    return v + __int_as_float(r);
}
__device__ __forceinline__ float sum16(float v) {
    v = row_ror_add<0x128>(v);   // row_ror:8
    v = row_ror_add<0x124>(v);   // row_ror:4
    v = row_ror_add<0x122>(v);   // row_ror:2
    v = row_ror_add<0x121>(v);   // row_ror:1
    return v;
}

// ---- weight prep: W[K][512] fp32 -> Wt[n][k] bf16, zero-padded to Kpad ----
// (hidden layers are called with W pre-offset by 2 rows and K == Kpad == 512)
__global__ __launch_bounds__(256) void prep_w(const float* __restrict__ W,
                                              ushort_t* __restrict__ dst,
                                              int K, int Kpad) {
    int n = blockIdx.x;            // 0..511
    for (int k = threadIdx.x; k < Kpad; k += 256) {
        float v = (k < K) ? W[k * 512 + n] : 0.0f;
        dst[n * Kpad + k] = f2bf(v);
    }
}

// One fused layer.
//   L0:    tangent GEMMs skipped — tangent pre-acts are W0 rows 2,3 directly.
//   !L0:   GEMM K = 512 exactly (activations only). te/pos contribution
//          (te*W[0,:] + pos*W[1,:]) is a rank-2 bias folded in as 2 f32 FMAs
//          per primal output (f32-exact; removes the old k=512,513 MFMA step
//          and tangent zero rows entirely).
//   LAST:  fuse the final 514->2 linear + divergence into the epilogue.
// Barrier structure per layer: [GEMM, stats, sbuf write] -> barrier A ->
// [wave-redundant finalize -> pwave, epilogue, A_s/dsum writes] -> barrier B.
template<int KPAD, bool L0, bool LAST>
__device__ __forceinline__ void do_layer(
    const ushort_t* __restrict__ Wt, const float* __restrict__ Wfull, float te,
    const float* __restrict__ bb,
    const float* __restrict__ gg, const float* __restrict__ bev,
    ushort_t* A_s, float* sbuf /*[16][68]*/, float* pwave /*[8][16][8]*/,
    float* dsum /*[16][36]*/, const float* W3s /*[514*2]*/)
{
    const int tid  = threadIdx.x;
    const int w    = tid >> 6;      // wave 0..7
    const int lane = tid & 63;
    const int q    = lane >> 4;     // quad 0..3
    const int c16  = lane & 15;
    const int nb   = w * 64;        // wave's 64-column base

    constexpr int MT  = L0 ? 1 : 3;         // m-tiles in the GEMM
    constexpr int NKS = KPAD / 32;          // K steps (L0: 5, hidden: 16)

    f32x4 acc[MT][4];
#pragma unroll
    for (int m = 0; m < MT; m++)
#pragma unroll
        for (int j = 0; j < 4; j++) acc[m][j] = (f32x4){0.f, 0.f, 0.f, 0.f};

    const int koff = q * 8;
    const ushort_t* bp = Wt + (nb + c16) * KPAD + koff;
    const ushort_t* ap = A_s + c16 * SROW + koff;

#pragma unroll
    for (int ks = 0; ks < NKS; ks++) {
        bf16x8 af[MT], bf[4];
#pragma unroll
        for (int m = 0; m < MT; m++)
            af[m] = *(const bf16x8*)(ap + m * 16 * SROW + ks * 32);
#pragma unroll
        for (int j = 0; j < 4; j++)
            bf[j] = *(const bf16x8*)(bp + j * 16 * KPAD + ks * 32);
#pragma unroll
        for (int m = 0; m < MT; m++)
#pragma unroll
            for (int j = 0; j < 4; j++)
                acc[m][j] = __builtin_amdgcn_mfma_f32_16x16x32_bf16(af[m], bf[j], acc[m][j], 0, 0, 0);
    }

    // L0: tangent pre-activations direct from W0 rows 2,3 (token-independent).
    // !L0: te/pos fold vectors from W rows 0,1 (f32, L2-resident).
    float tu0[4], tu1[4];
    float w0te[4], w1v[4];
#pragma unroll
    for (int j = 0; j < 4; j++) {
        int n = nb + 16 * j + c16;
        if constexpr (L0) {
            tu0[j] = Wfull[2 * 512 + n];
            tu1[j] = Wfull[3 * 512 + n];
        } else {
            w0te[j] = te * Wfull[n];        // row 0 (te)
            w1v[j]  = Wfull[512 + n];       // row 1 (pos)
        }
    }

    // per-token pos values for this wave's 4 r-slots (token = 4q+r)
    const int si0 = (blockIdx.x * TM) & 63;     // no wrap within a block (16|64)
    float posr[4];
#pragma unroll
    for (int r = 0; r < 4; r++)
        posr[r] = (float)(si0 + 4 * q + r + 1) * (1.0f / 64.0f);

    // bias (+ te/pos rank-2 fold for hidden layers) on primal rows
#pragma unroll
    for (int j = 0; j < 4; j++) {
        float bv = bb[nb + 16 * j + c16];
        if constexpr (!L0) bv += w0te[j];
#pragma unroll
        for (int r = 0; r < 4; r++)
            acc[0][j][r] += L0 ? bv : fmaf(posr[r], w1v[j], bv);
    }

    // wave-local LN stats (6 sums per token over this wave's 64 cols) — DPP all-reduce
    float st[4][6];
#pragma unroll
    for (int r = 0; r < 4; r++) {
        float s1 = 0.f, s2 = 0.f, a0 = 0.f, x0 = 0.f, a1 = 0.f, x1 = 0.f;
#pragma unroll
        for (int j = 0; j < 4; j++) {
            float p  = acc[0][j][r];
            float u0 = L0 ? tu0[j] : acc[1 % MT][j][r];
            float u1 = L0 ? tu1[j] : acc[2 % MT][j][r];
            s1 += p; s2 += p * p;
            a0 += u0; x0 += p * u0;
            a1 += u1; x1 += p * u1;
        }
        st[r][0] = s1; st[r][1] = s2; st[r][2] = a0; st[r][3] = x0; st[r][4] = a1; st[r][5] = x1;
    }
#pragma unroll
    for (int r = 0; r < 4; r++)
#pragma unroll
        for (int s = 0; s < 6; s++) st[r][s] = sum16(st[r][s]);
    if (c16 == 0) {
#pragma unroll
        for (int r = 0; r < 4; r++) {
            int tok = 4 * q + r;
            *(float4*)&sbuf[tok * 68 + w * 8]     = (float4){st[r][0], st[r][1], st[r][2], st[r][3]};
            *(float2*)&sbuf[tok * 68 + w * 8 + 4] = (float2){st[r][4], st[r][5]};
        }
    }
    __syncthreads();   // barrier A: sbuf cross-wave; also fences GEMM A_s reads

    // finalize: wave-redundant (every wave, lanes 0-15), wave-private pwave.
    if (lane < 16) {
        int tok = lane;
        float s0 = 0.f, s1 = 0.f, s2 = 0.f, s3 = 0.f, s4 = 0.f, s5 = 0.f;
#pragma unroll
        for (int ww = 0; ww < 8; ww++) {
            float4 a = *(const float4*)&sbuf[tok * 68 + ww * 8];
            float2 b = *(const float2*)&sbuf[tok * 68 + ww * 8 + 4];
            s0 += a.x; s1 += a.y; s2 += a.z; s3 += a.w; s4 += b.x; s5 += b.y;
        }
        const float inv = 1.0f / 512.0f;
        float mu  = s0 * inv;
        float var = s1 * inv - mu * mu;
        float rs  = rsqrtf(var + EPS);
        float dm0 = s2 * inv, dm1 = s4 * inv;
        float c0 = rs * (s3 * inv - mu * dm0);
        float c1 = rs * (s5 * inv - mu * dm1);
        *(float4*)&pwave[(w * 16 + tok) * 8]     = (float4){mu, rs, dm0, c0};
        *(float4*)&pwave[(w * 16 + tok) * 8 + 4] = (float4){dm1, c1, 0.f, 0.f};
    }

    // epilogue: softplus(LN) + JVP; non-LAST writes bf16 to A_s k[0,512),
    // LAST fuses the W3 dot (full f32) into per-wave partials.
    float gv[4], bvv[4];
#pragma unroll
    for (int j = 0; j < 4; j++) {
        gv[j]  = gg[nb + 16 * j + c16];
        bvv[j] = bev[nb + 16 * j + c16];
    }
#pragma unroll
    for (int r = 0; r < 4; r++) {
        int tok = 4 * q + r;
        float4 pa = *(const float4*)&pwave[(w * 16 + tok) * 8];
        float4 pb = *(const float4*)&pwave[(w * 16 + tok) * 8 + 4];
        float mu = pa.x, rs = pa.y, dm0 = pa.z, c0 = pa.w;
        float dm1 = pb.x, c1 = pb.y;
        float spv[4], d0v[4], d1v[4];
        float a0p = 0.f, a1p = 0.f, dvp = 0.f;
#pragma unroll
        for (int j = 0; j < 4; j++) {
            float p  = acc[0][j][r];
            float u0 = L0 ? tu0[j] : acc[1 % MT][j][r];
            float u1 = L0 ? tu1[j] : acc[2 % MT][j][r];
            float xh = (p - mu) * rs;
            float y  = fmaf(xh, gv[j], bvv[j]);
            float e  = __expf(-fabsf(y));
            float ope  = 1.0f + e;
            float rinv = fastrcp(ope);
            float sig  = (y >= 0.f) ? rinv : e * rinv;
            float sp   = fmaxf(y, 0.f) + __logf(ope);
            float sgrs = sig * (gv[j] * rs);
            float d0 = sgrs * fmaf(-xh, c0, u0 - dm0);
            float d1 = sgrs * fmaf(-xh, c1, u1 - dm1);
            if constexpr (LAST) {
                float2 wv = *(const float2*)&W3s[(2 + nb + 16 * j + c16) * 2];
                a0p = fmaf(sp, wv.x, a0p);
                a1p = fmaf(sp, wv.y, a1p);
                dvp = fmaf(d0, wv.x, dvp);
                dvp = fmaf(d1, wv.y, dvp);
            } else {
                spv[j] = sp; d0v[j] = d0; d1v[j] = d1;
            }
        }
        if constexpr (LAST) {
            a0p = sum16(a0p); a1p = sum16(a1p); dvp = sum16(dvp);
            if (c16 == 0) {
                dsum[tok * 36 + w * 4 + 0] = a0p;
                dsum[tok * 36 + w * 4 + 1] = a1p;
                dsum[tok * 36 + w * 4 + 2] = dvp;
            }
        } else {
            uint_t ps01 = pk_bf16(spv[0], spv[1]), ps23 = pk_bf16(spv[2], spv[3]);
            uint_t p001 = pk_bf16(d0v[0], d0v[1]), p023 = pk_bf16(d0v[2], d0v[3]);
            uint_t p101 = pk_bf16(d1v[0], d1v[1]), p123 = pk_bf16(d1v[2], d1v[3]);
            int n0 = nb + c16;
            ushort_t* xr  = A_s + tok * SROW + n0;          // k in [0,512) now
            ushort_t* u0r = xr + 16 * SROW;
            ushort_t* u1r = xr + 32 * SROW;
            xr[0]  = (ushort_t)ps01;  xr[16]  = (ushort_t)(ps01 >> 16);
            xr[32] = (ushort_t)ps23;  xr[48]  = (ushort_t)(ps23 >> 16);
            u0r[0] = (ushort_t)p001;  u0r[16] = (ushort_t)(p001 >> 16);
            u0r[32] = (ushort_t)p023; u0r[48] = (ushort_t)(p023 >> 16);
            u1r[0] = (ushort_t)p101;  u1r[16] = (ushort_t)(p101 >> 16);
            u1r[32] = (ushort_t)p123; u1r[48] = (ushort_t)(p123 >> 16);
        }
    }
    __syncthreads();   // barrier B: A_s (non-LAST) / dsum (LAST) cross-wave
}

__global__ __launch_bounds__(512, 4) void ode_mfma(
    const float* __restrict__ t, const float* __restrict__ z, const float* __restrict__ cond,
    const ushort_t* __restrict__ Wt0, const ushort_t* __restrict__ Wt1, const ushort_t* __restrict__ Wt2,
    const float* __restrict__ W0full, const float* __restrict__ W1full, const float* __restrict__ W2full,
    const float* __restrict__ b0, const float* __restrict__ g0, const float* __restrict__ be0,
    const float* __restrict__ b1, const float* __restrict__ g1, const float* __restrict__ be1,
    const float* __restrict__ b2, const float* __restrict__ g2, const float* __restrict__ be2,
    const float* __restrict__ W3, const float* __restrict__ b3,
    float* __restrict__ out)
{
    __shared__ ushort_t A_s[48 * SROW];     // rows 0..15 primal x, 16..31 u0, 32..47 u1
    __shared__ float sbuf[16 * 68];         // [tok][w*8+s], stride 68 -> 2-way banks
    __shared__ float pwave[8 * 16 * 8];     // wave-private LN params [w][tok][8]
    __shared__ float dsum[16 * 36];         // [tok][w*4+c] L3 partials, stride 36
    __shared__ float W3s[514 * 2];          // staged W3 (row-major [514][2])
    // 2 blocks/CU (reg-capped: 64 arch VGPR + 64 AGPR = 128/wave -> 4 waves/SIMD).

    const int tid = threadIdx.x;
    const float te = t[0];

    // ---------------- init: targeted zeroing + data + W3 staging, ONE barrier ----
    // Only the L0 primal pad k[132,160) must read as zero; tangent rows are fully
    // written by the L0 epilogue (te/pos tangent rows no longer exist in the GEMM).
    if (tid < 256) {
        int row = tid >> 4, k2 = tid & 15;
        *(uint_t*)(A_s + row * SROW + 132 + 2 * k2) = 0u;   // primal k[132,164)
    }
    if (tid < TM) {
        int tok = tid;
        int gm  = blockIdx.x * TM + tok;
        int si  = gm & 63;
        float pos = (float)(si + 1) * (1.0f / 64.0f);
        A_s[tok * SROW + 0] = f2bf(te);
        A_s[tok * SROW + 1] = f2bf(pos);
        A_s[tok * SROW + 2] = f2bf(z[gm * 2 + 0]);
        A_s[tok * SROW + 3] = f2bf(z[gm * 2 + 1]);
    }
    {   // all 16 tokens of a block share one batch row (16 | 64)
        int bi = (blockIdx.x * TM) >> 6;
        for (int i = tid; i < TM * 128; i += 512) {
            int tok = i >> 7, c = i & 127;
            A_s[tok * SROW + 4 + c] = f2bf(cond[bi * 128 + c]);
        }
    }
    for (int i = tid; i < 514 * 2; i += 512) W3s[i] = W3[i];
    __syncthreads();

    do_layer<K0P, true , false>(Wt0, W0full, te, b0, g0, be0, A_s, sbuf, pwave, nullptr, nullptr);
    do_layer<KHP, false, false>(Wt1, W1full, te, b1, g1, be1, A_s, sbuf, pwave, nullptr, nullptr);
    do_layer<KHP, false, true >(Wt2, W2full, te, b2, g2, be2, A_s, sbuf, pwave, dsum, W3s);

    // ---------------- final cross-wave reduce of L3 partials ----------------
    if (tid < 64) {
        int tok = tid >> 2, c = tid & 3;
        if (c < 3) {
            float s = 0.f;
#pragma unroll
            for (int ww = 0; ww < 8; ww++) s += dsum[tok * 36 + ww * 4 + c];
            int gm = blockIdx.x * TM + tok;
            if (c == 0) {
                float pos = (float)((gm & 63) + 1) * (1.0f / 64.0f);
                out[gm * 2 + 0] = s + te * W3s[0] + pos * W3s[2] + b3[0];
            } else if (c == 1) {
                float pos = (float)((gm & 63) + 1) * (1.0f / 64.0f);
                out[gm * 2 + 1] = s + te * W3s[1] + pos * W3s[3] + b3[1];
            } else {
                out[NTOK * 2 + gm] = -s;
            }
        }
    }
}

extern "C" void kernel_launch(void* const* d_in, const int* in_sizes, int n_in,
                              void* d_out, int out_size, void* d_ws, size_t ws_size,
                              hipStream_t stream) {
    const float* t    = (const float*)d_in[0];
    const float* z    = (const float*)d_in[1];
    const float* cond = (const float*)d_in[2];
    const float* W0   = (const float*)d_in[3];
    const float* b0   = (const float*)d_in[4];
    const float* g0   = (const float*)d_in[5];
    const float* be0  = (const float*)d_in[6];
    const float* W1   = (const float*)d_in[7];
    const float* b1   = (const float*)d_in[8];
    const float* g1   = (const float*)d_in[9];
    const float* be1  = (const float*)d_in[10];
    const float* W2   = (const float*)d_in[11];
    const float* b2   = (const float*)d_in[12];
    const float* g2   = (const float*)d_in[13];
    const float* be2  = (const float*)d_in[14];
    const float* W3   = (const float*)d_in[15];
    const float* b3   = (const float*)d_in[16];
    float* out = (float*)d_out;

    ushort_t* Wt0 = (ushort_t*)d_ws;                    // 512*160
    ushort_t* Wt1 = Wt0 + 512 * K0P;                    // 512*512
    ushort_t* Wt2 = Wt1 + 512 * KHP;                    // 512*512

    hipLaunchKernelGGL(prep_w, dim3(512), dim3(256), 0, stream, W0, Wt0, 132, K0P);
    // hidden layers: skip rows 0,1 (te,pos — folded into the epilogue bias)
    hipLaunchKernelGGL(prep_w, dim3(512), dim3(256), 0, stream, W1 + 2 * 512, Wt1, 512, KHP);
    hipLaunchKernelGGL(prep_w, dim3(512), dim3(256), 0, stream, W2 + 2 * 512, Wt2, 512, KHP);

    hipLaunchKernelGGL(ode_mfma, dim3(NTOK / TM), dim3(512), 0, stream,
                       t, z, cond, Wt0, Wt1, Wt2, W0, W1, W2,
                       b0, g0, be0, b1, g1, be1, b2, g2, be2, W3, b3, out);
}

// Round 5
// 843.451 us; speedup vs baseline: 1.4471x; 1.4471x over previous
//
#include <hip/hip_runtime.h>
#include <math.h>

typedef unsigned short ushort_t;
typedef unsigned int uint_t;
typedef __attribute__((ext_vector_type(8))) short bf16x8;
typedef __attribute__((ext_vector_type(4))) float f32x4;

#define NTOK 131072          // B*S
#define TM 16                // tokens per block
// SROW 520: 1040 B row = 65*16 -> b128 16B-aligned; 260 dw == 4 mod 32 -> free
// 2-way bank pattern (SROW=512 would be a 16-way conflict: 256 dw == 0 mod 32).
#define SROW 520
#define K0P 160              // layer0 Wt row stride AND K extent (132 -> 160)
#define KHS 544              // hidden Wt row STRIDE (1088 B, odd multiple of 32B).
                             // K extent read is 512 (te/pos folded out). Stride
                             // 512 (1024 B, pow2) serializes L2 channels: R4 was
                             // +244 us with LESS work. Keep stride non-pow2.
#define EPS 1e-5f

__device__ __forceinline__ ushort_t f2bf(float f) {
    uint_t x = __float_as_uint(f);
    x += 0x7FFFu + ((x >> 16) & 1u);   // RNE
    return (ushort_t)(x >> 16);
}
__device__ __forceinline__ float bf2f(ushort_t u) {
    return __uint_as_float(((uint_t)u) << 16);
}

#if defined(__has_builtin)
#  if __has_builtin(__builtin_amdgcn_cvt_pk_bf16_f32)
#    define HAVE_PK_BF16 1
#  endif
#  if __has_builtin(__builtin_amdgcn_rcpf)
#    define HAVE_RCPF 1
#  endif
#endif
__device__ __forceinline__ uint_t pk_bf16(float a, float b) {
#ifdef HAVE_PK_BF16
    auto r = __builtin_amdgcn_cvt_pk_bf16_f32(a, b);
    union { decltype(r) v; uint_t u; } cv; cv.v = r;
    return cv.u;
#else
    return (uint_t)f2bf(a) | ((uint_t)f2bf(b) << 16);
#endif
}
// approx reciprocal: v_rcp_f32 (1 op) instead of IEEE div (~9 ops). ~1 ulp —
// outputs are bf16-rounded, tolerance 1.2e-2; exactness not needed.
__device__ __forceinline__ float fastrcp(float x) {
#ifdef HAVE_RCPF
    return __builtin_amdgcn_rcpf(x);
#else
    return 1.0f / x;
#endif
}

// ---- DPP 16-lane rotation-reduction (all-reduce within each 16-lane row) ----
template<int CTRL>
__device__ __forceinline__ float row_ror_add(float v) {
    int r = __builtin_amdgcn_update_dpp(0, __float_as_int(v), CTRL, 0xF, 0xF, true);
    return v + __int_as_float(r);
}
__device__ __forceinline__ float sum16(float v) {
    v = row_ror_add<0x128>(v);   // row_ror:8
    v = row_ror_add<0x124>(v);   // row_ror:4
    v = row_ror_add<0x122>(v);   // row_ror:2
    v = row_ror_add<0x121>(v);   // row_ror:1
    return v;
}

// ---- weight prep: W[K][512] fp32 -> Wt[n][k] bf16, zero-padded to Kpad ----
// (hidden layers are called with W pre-offset by 2 rows; K=512 < Kpad=544)
__global__ __launch_bounds__(256) void prep_w(const float* __restrict__ W,
                                              ushort_t* __restrict__ dst,
                                              int K, int Kpad) {
    int n = blockIdx.x;            // 0..511
    for (int k = threadIdx.x; k < Kpad; k += 256) {
        float v = (k < K) ? W[k * 512 + n] : 0.0f;
        dst[n * Kpad + k] = f2bf(v);
    }
}

// One fused layer.
//   L0:    tangent GEMMs skipped — tangent pre-acts are W0 rows 2,3 directly.
//   !L0:   GEMM K = 512 exactly (activations only, 16 steps). te/pos
//          contribution (te*W[0,:] + pos*W[1,:]) is a rank-2 bias folded into
//          the accumulator epilogue as f32 FMAs (exact).
//   LAST:  fuse the final 514->2 linear + divergence into the epilogue.
// KPAD is the Wt row STRIDE (non-pow2!); NKS the K-step count actually read.
// Barrier structure per layer: [GEMM, stats, sbuf write] -> barrier A ->
// [wave-redundant finalize -> pwave, epilogue, A_s/dsum writes] -> barrier B.
template<int KPAD, bool L0, bool LAST>
__device__ __forceinline__ void do_layer(
    const ushort_t* __restrict__ Wt, const float* __restrict__ Wfull, float te,
    const float* __restrict__ bb,
    const float* __restrict__ gg, const float* __restrict__ bev,
    ushort_t* A_s, float* sbuf /*[16][68]*/, float* pwave /*[8][16][8]*/,
    float* dsum /*[16][36]*/, const float* W3s /*[514*2]*/)
{
    const int tid  = threadIdx.x;
    const int w    = tid >> 6;      // wave 0..7
    const int lane = tid & 63;
    const int q    = lane >> 4;     // quad 0..3
    const int c16  = lane & 15;
    const int nb   = w * 64;        // wave's 64-column base

    constexpr int MT  = L0 ? 1 : 3;         // m-tiles in the GEMM
    constexpr int NKS = L0 ? (K0P / 32) : 16;   // K steps actually read

    f32x4 acc[MT][4];
#pragma unroll
    for (int m = 0; m < MT; m++)
#pragma unroll
        for (int j = 0; j < 4; j++) acc[m][j] = (f32x4){0.f, 0.f, 0.f, 0.f};

    const int koff = q * 8;
    const ushort_t* bp = Wt + (nb + c16) * KPAD + koff;
    const ushort_t* ap = A_s + c16 * SROW + koff;

#pragma unroll
    for (int ks = 0; ks < NKS; ks++) {
        bf16x8 af[MT], bf[4];
#pragma unroll
        for (int m = 0; m < MT; m++)
            af[m] = *(const bf16x8*)(ap + m * 16 * SROW + ks * 32);
#pragma unroll
        for (int j = 0; j < 4; j++)
            bf[j] = *(const bf16x8*)(bp + j * 16 * KPAD + ks * 32);
#pragma unroll
        for (int m = 0; m < MT; m++)
#pragma unroll
            for (int j = 0; j < 4; j++)
                acc[m][j] = __builtin_amdgcn_mfma_f32_16x16x32_bf16(af[m], bf[j], acc[m][j], 0, 0, 0);
    }

    // L0: tangent pre-activations direct from W0 rows 2,3 (token-independent).
    // !L0: te/pos fold vectors from W rows 0,1 (f32, L2-resident).
    float tu0[4], tu1[4];
    float w0te[4], w1v[4];
#pragma unroll
    for (int j = 0; j < 4; j++) {
        int n = nb + 16 * j + c16;
        if constexpr (L0) {
            tu0[j] = Wfull[2 * 512 + n];
            tu1[j] = Wfull[3 * 512 + n];
        } else {
            w0te[j] = te * Wfull[n];        // row 0 (te)
            w1v[j]  = Wfull[512 + n];       // row 1 (pos)
        }
    }

    // per-token pos values for this wave's 4 r-slots (token = 4q+r)
    const int si0 = (blockIdx.x * TM) & 63;     // no wrap within a block (16|64)
    float posr[4];
#pragma unroll
    for (int r = 0; r < 4; r++)
        posr[r] = (float)(si0 + 4 * q + r + 1) * (1.0f / 64.0f);

    // bias (+ te/pos rank-2 fold for hidden layers) on primal rows
#pragma unroll
    for (int j = 0; j < 4; j++) {
        float bv = bb[nb + 16 * j + c16];
        if constexpr (!L0) bv += w0te[j];
#pragma unroll
        for (int r = 0; r < 4; r++)
            acc[0][j][r] += L0 ? bv : fmaf(posr[r], w1v[j], bv);
    }

    // wave-local LN stats (6 sums per token over this wave's 64 cols) — DPP all-reduce
    float st[4][6];
#pragma unroll
    for (int r = 0; r < 4; r++) {
        float s1 = 0.f, s2 = 0.f, a0 = 0.f, x0 = 0.f, a1 = 0.f, x1 = 0.f;
#pragma unroll
        for (int j = 0; j < 4; j++) {
            float p  = acc[0][j][r];
            float u0 = L0 ? tu0[j] : acc[1 % MT][j][r];
            float u1 = L0 ? tu1[j] : acc[2 % MT][j][r];
            s1 += p; s2 += p * p;
            a0 += u0; x0 += p * u0;
            a1 += u1; x1 += p * u1;
        }
        st[r][0] = s1; st[r][1] = s2; st[r][2] = a0; st[r][3] = x0; st[r][4] = a1; st[r][5] = x1;
    }
#pragma unroll
    for (int r = 0; r < 4; r++)
#pragma unroll
        for (int s = 0; s < 6; s++) st[r][s] = sum16(st[r][s]);
    if (c16 == 0) {
#pragma unroll
        for (int r = 0; r < 4; r++) {
            int tok = 4 * q + r;
            *(float4*)&sbuf[tok * 68 + w * 8]     = (float4){st[r][0], st[r][1], st[r][2], st[r][3]};
            *(float2*)&sbuf[tok * 68 + w * 8 + 4] = (float2){st[r][4], st[r][5]};
        }
    }
    __syncthreads();   // barrier A: sbuf cross-wave; also fences GEMM A_s reads

    // finalize: wave-redundant (every wave, lanes 0-15), wave-private pwave.
    if (lane < 16) {
        int tok = lane;
        float s0 = 0.f, s1 = 0.f, s2 = 0.f, s3 = 0.f, s4 = 0.f, s5 = 0.f;
#pragma unroll
        for (int ww = 0; ww < 8; ww++) {
            float4 a = *(const float4*)&sbuf[tok * 68 + ww * 8];
            float2 b = *(const float2*)&sbuf[tok * 68 + ww * 8 + 4];
            s0 += a.x; s1 += a.y; s2 += a.z; s3 += a.w; s4 += b.x; s5 += b.y;
        }
        const float inv = 1.0f / 512.0f;
        float mu  = s0 * inv;
        float var = s1 * inv - mu * mu;
        float rs  = rsqrtf(var + EPS);
        float dm0 = s2 * inv, dm1 = s4 * inv;
        float c0 = rs * (s3 * inv - mu * dm0);
        float c1 = rs * (s5 * inv - mu * dm1);
        *(float4*)&pwave[(w * 16 + tok) * 8]     = (float4){mu, rs, dm0, c0};
        *(float4*)&pwave[(w * 16 + tok) * 8 + 4] = (float4){dm1, c1, 0.f, 0.f};
    }

    // epilogue: softplus(LN) + JVP; non-LAST writes bf16 to A_s k[0,512),
    // LAST fuses the W3 dot (full f32) into per-wave partials.
    float gv[4], bvv[4];
#pragma unroll
    for (int j = 0; j < 4; j++) {
        gv[j]  = gg[nb + 16 * j + c16];
        bvv[j] = bev[nb + 16 * j + c16];
    }
#pragma unroll
    for (int r = 0; r < 4; r++) {
        int tok = 4 * q + r;
        float4 pa = *(const float4*)&pwave[(w * 16 + tok) * 8];
        float4 pb = *(const float4*)&pwave[(w * 16 + tok) * 8 + 4];
        float mu = pa.x, rs = pa.y, dm0 = pa.z, c0 = pa.w;
        float dm1 = pb.x, c1 = pb.y;
        float spv[4], d0v[4], d1v[4];
        float a0p = 0.f, a1p = 0.f, dvp = 0.f;
#pragma unroll
        for (int j = 0; j < 4; j++) {
            float p  = acc[0][j][r];
            float u0 = L0 ? tu0[j] : acc[1 % MT][j][r];
            float u1 = L0 ? tu1[j] : acc[2 % MT][j][r];
            float xh = (p - mu) * rs;
            float y  = fmaf(xh, gv[j], bvv[j]);
            float e  = __expf(-fabsf(y));
            float ope  = 1.0f + e;
            float rinv = fastrcp(ope);
            float sig  = (y >= 0.f) ? rinv : e * rinv;
            float sp   = fmaxf(y, 0.f) + __logf(ope);
            float sgrs = sig * (gv[j] * rs);
            float d0 = sgrs * fmaf(-xh, c0, u0 - dm0);
            float d1 = sgrs * fmaf(-xh, c1, u1 - dm1);
            if constexpr (LAST) {
                float2 wv = *(const float2*)&W3s[(2 + nb + 16 * j + c16) * 2];
                a0p = fmaf(sp, wv.x, a0p);
                a1p = fmaf(sp, wv.y, a1p);
                dvp = fmaf(d0, wv.x, dvp);
                dvp = fmaf(d1, wv.y, dvp);
            } else {
                spv[j] = sp; d0v[j] = d0; d1v[j] = d1;
            }
        }
        if constexpr (LAST) {
            a0p = sum16(a0p); a1p = sum16(a1p); dvp = sum16(dvp);
            if (c16 == 0) {
                dsum[tok * 36 + w * 4 + 0] = a0p;
                dsum[tok * 36 + w * 4 + 1] = a1p;
                dsum[tok * 36 + w * 4 + 2] = dvp;
            }
        } else {
            uint_t ps01 = pk_bf16(spv[0], spv[1]), ps23 = pk_bf16(spv[2], spv[3]);
            uint_t p001 = pk_bf16(d0v[0], d0v[1]), p023 = pk_bf16(d0v[2], d0v[3]);
            uint_t p101 = pk_bf16(d1v[0], d1v[1]), p123 = pk_bf16(d1v[2], d1v[3]);
            int n0 = nb + c16;
            ushort_t* xr  = A_s + tok * SROW + n0;          // k in [0,512)
            ushort_t* u0r = xr + 16 * SROW;
            ushort_t* u1r = xr + 32 * SROW;
            xr[0]  = (ushort_t)ps01;  xr[16]  = (ushort_t)(ps01 >> 16);
            xr[32] = (ushort_t)ps23;  xr[48]  = (ushort_t)(ps23 >> 16);
            u0r[0] = (ushort_t)p001;  u0r[16] = (ushort_t)(p001 >> 16);
            u0r[32] = (ushort_t)p023; u0r[48] = (ushort_t)(p023 >> 16);
            u1r[0] = (ushort_t)p101;  u1r[16] = (ushort_t)(p101 >> 16);
            u1r[32] = (ushort_t)p123; u1r[48] = (ushort_t)(p123 >> 16);
        }
    }
    __syncthreads();   // barrier B: A_s (non-LAST) / dsum (LAST) cross-wave
}

__global__ __launch_bounds__(512, 4) void ode_mfma(
    const float* __restrict__ t, const float* __restrict__ z, const float* __restrict__ cond,
    const ushort_t* __restrict__ Wt0, const ushort_t* __restrict__ Wt1, const ushort_t* __restrict__ Wt2,
    const float* __restrict__ W0full, const float* __restrict__ W1full, const float* __restrict__ W2full,
    const float* __restrict__ b0, const float* __restrict__ g0, const float* __restrict__ be0,
    const float* __restrict__ b1, const float* __restrict__ g1, const float* __restrict__ be1,
    const float* __restrict__ b2, const float* __restrict__ g2, const float* __restrict__ be2,
    const float* __restrict__ W3, const float* __restrict__ b3,
    float* __restrict__ out)
{
    __shared__ ushort_t A_s[48 * SROW];     // rows 0..15 primal x, 16..31 u0, 32..47 u1
    __shared__ float sbuf[16 * 68];         // [tok][w*8+s], stride 68 -> 2-way banks
    __shared__ float pwave[8 * 16 * 8];     // wave-private LN params [w][tok][8]
    __shared__ float dsum[16 * 36];         // [tok][w*4+c] L3 partials, stride 36
    __shared__ float W3s[514 * 2];          // staged W3 (row-major [514][2])
    // 2 blocks/CU (reg-capped: 64 arch VGPR + 64 AGPR = 128/wave -> 4 waves/SIMD).

    const int tid = threadIdx.x;
    const float te = t[0];

    // ---------------- init: targeted zeroing + data + W3 staging, ONE barrier ----
    // Only the L0 primal pad k[132,160) must read as zero; tangent rows are fully
    // written by the L0 epilogue (te/pos tangent rows no longer exist in the GEMM).
    if (tid < 256) {
        int row = tid >> 4, k2 = tid & 15;
        *(uint_t*)(A_s + row * SROW + 132 + 2 * k2) = 0u;   // primal k[132,164)
    }
    if (tid < TM) {
        int tok = tid;
        int gm  = blockIdx.x * TM + tok;
        int si  = gm & 63;
        float pos = (float)(si + 1) * (1.0f / 64.0f);
        A_s[tok * SROW + 0] = f2bf(te);
        A_s[tok * SROW + 1] = f2bf(pos);
        A_s[tok * SROW + 2] = f2bf(z[gm * 2 + 0]);
        A_s[tok * SROW + 3] = f2bf(z[gm * 2 + 1]);
    }
    {   // all 16 tokens of a block share one batch row (16 | 64)
        int bi = (blockIdx.x * TM) >> 6;
        for (int i = tid; i < TM * 128; i += 512) {
            int tok = i >> 7, c = i & 127;
            A_s[tok * SROW + 4 + c] = f2bf(cond[bi * 128 + c]);
        }
    }
    for (int i = tid; i < 514 * 2; i += 512) W3s[i] = W3[i];
    __syncthreads();

    do_layer<K0P, true , false>(Wt0, W0full, te, b0, g0, be0, A_s, sbuf, pwave, nullptr, nullptr);
    do_layer<KHS, false, false>(Wt1, W1full, te, b1, g1, be1, A_s, sbuf, pwave, nullptr, nullptr);
    do_layer<KHS, false, true >(Wt2, W2full, te, b2, g2, be2, A_s, sbuf, pwave, dsum, W3s);

    // ---------------- final cross-wave reduce of L3 partials ----------------
    if (tid < 64) {
        int tok = tid >> 2, c = tid & 3;
        if (c < 3) {
            float s = 0.f;
#pragma unroll
            for (int ww = 0; ww < 8; ww++) s += dsum[tok * 36 + ww * 4 + c];
            int gm = blockIdx.x * TM + tok;
            if (c == 0) {
                float pos = (float)((gm & 63) + 1) * (1.0f / 64.0f);
                out[gm * 2 + 0] = s + te * W3s[0] + pos * W3s[2] + b3[0];
            } else if (c == 1) {
                float pos = (float)((gm & 63) + 1) * (1.0f / 64.0f);
                out[gm * 2 + 1] = s + te * W3s[1] + pos * W3s[3] + b3[1];
            } else {
                out[NTOK * 2 + gm] = -s;
            }
        }
    }
}

extern "C" void kernel_launch(void* const* d_in, const int* in_sizes, int n_in,
                              void* d_out, int out_size, void* d_ws, size_t ws_size,
                              hipStream_t stream) {
    const float* t    = (const float*)d_in[0];
    const float* z    = (const float*)d_in[1];
    const float* cond = (const float*)d_in[2];
    const float* W0   = (const float*)d_in[3];
    const float* b0   = (const float*)d_in[4];
    const float* g0   = (const float*)d_in[5];
    const float* be0  = (const float*)d_in[6];
    const float* W1   = (const float*)d_in[7];
    const float* b1   = (const float*)d_in[8];
    const float* g1   = (const float*)d_in[9];
    const float* be1  = (const float*)d_in[10];
    const float* W2   = (const float*)d_in[11];
    const float* b2   = (const float*)d_in[12];
    const float* g2   = (const float*)d_in[13];
    const float* be2  = (const float*)d_in[14];
    const float* W3   = (const float*)d_in[15];
    const float* b3   = (const float*)d_in[16];
    float* out = (float*)d_out;

    ushort_t* Wt0 = (ushort_t*)d_ws;                    // 512*160
    ushort_t* Wt1 = Wt0 + 512 * K0P;                    // 512*544 (stride 544, data 512)
    ushort_t* Wt2 = Wt1 + 512 * KHS;                    // 512*544

    hipLaunchKernelGGL(prep_w, dim3(512), dim3(256), 0, stream, W0, Wt0, 132, K0P);
    // hidden layers: skip rows 0,1 (te,pos — folded into the epilogue bias);
    // stride stays 544 (non-pow2), rows [512,544) zero-filled and never read.
    hipLaunchKernelGGL(prep_w, dim3(512), dim3(256), 0, stream, W1 + 2 * 512, Wt1, 512, KHS);
    hipLaunchKernelGGL(prep_w, dim3(512), dim3(256), 0, stream, W2 + 2 * 512, Wt2, 512, KHS);

    hipLaunchKernelGGL(ode_mfma, dim3(NTOK / TM), dim3(512), 0, stream,
                       t, z, cond, Wt0, Wt1, Wt2, W0, W1, W2,
                       b0, g0, be0, b1, g1, be1, b2, g2, be2, W3, b3, out);
}